// Round 4
// baseline (241.755 us; speedup 1.0000x reference)
//
#include <hip/hip_runtime.h>
#include <hip/hip_bf16.h>

#define VSZ 32000
#define DSZ 256
#define BSZ 32
#define MSZ 1024
#define TSZ 4
#define PSZ 1025
#define HOPS 3
#define VD (VSZ * DSZ)

// Workspace layout (float offsets)
#define OFF_POS   0                         // int[M*B]  (layout [m][b])
#define OFF_U     32768                     // float[B][D]
#define OFF_U0    40960
#define OFF_OK0   49152
#define OFF_PP    57344                     // float[P][B]  32800
#define OFF_GIH   90144                     // float[1536][32] = 49152
#define OFF_SC    139296                    // float[M][B] = 32768
#define OFF_W     172064                    // float[V][B] padded to 1,048,576
#define OFF_PART  1220640                   // float[250][B][D] = 2,048,000
#define OFF_PROJ  3268640                   // float[V][B] = 1,024,000
#define WS_END    4292640                   // ~17.2 MB

// Output layout (floats): prob_lg [B,M] | p_vocab [B,V] | hidden [1,B,D]
#define OUT_PV    (BSZ * MSZ)
#define OUT_HID   (OUT_PV + BSZ * VSZ)

// ---------------------------------------------------------------------------
// positions (layout [m][b]): ballot scan. 32 blocks x 1024 threads.
__global__ void k_positions(const int* __restrict__ story, int* __restrict__ pos) {
    int b = blockIdx.x;
    int m = threadIdx.x;
    __shared__ int wsum[16];
    int tok0 = story[(m * BSZ + b) * TSZ];
    int flag = (tok0 != 0) ? 1 : 0;
    unsigned long long mask = __ballot(flag);
    int lane = m & 63, wid = m >> 6;
    int pfx = __popcll(mask & ((1ULL << lane) - 1ULL));
    if (lane == 63) wsum[wid] = pfx + flag;
    __syncthreads();
    if (m == 0) {
        int run = 0;
        for (int i = 0; i < 16; ++i) { int v = wsum[i]; wsum[i] = run; run += v; }
    }
    __syncthreads();
    int incl = wsum[wid] + pfx + flag;
    pos[m * BSZ + b] = flag ? incl : 0;
}

// ---------------------------------------------------------------------------
// GRU matrix-vector as streamer GEMM: rows 0..767 = w_ih (vs x), 768..1535 = w_hh (vs h).
// 12 blocks x 256 thr; block handles 128 rows; gih[row][b].
__global__ __launch_bounds__(256) void k_gruMV(const int* __restrict__ encq,
                                               const float* __restrict__ lasth,
                                               const float* __restrict__ C0,
                                               const float* __restrict__ w_ih,
                                               const float* __restrict__ w_hh,
                                               float* __restrict__ gih) {
    __shared__ float xL[BSZ][DSZ];           // 32 KB
    int t = threadIdx.x;
    int blk = blockIdx.x;
    bool isX = blk < 6;
    for (int i = t; i < BSZ * 64; i += 256) {
        int b = i >> 6, c4 = i & 63;
        float4 v;
        if (isX) v = ((const float4*)&C0[(size_t)encq[b] * DSZ])[c4];
        else     v = ((const float4*)&lasth[b * DSZ])[c4];
        *(float4*)&xL[b][c4 * 4] = v;
    }
    __syncthreads();
    int lane = t & 63, bg = t >> 6, b0 = bg * 8;
    int r0 = blk * 128 + lane;               // global row, and r0+64
    int rl = isX ? r0 : (r0 - 768);
    const float* W = isX ? w_ih : w_hh;
    const float* w0p = W + (size_t)rl * DSZ;
    const float* w1p = w0p + (size_t)64 * DSZ;
    float acc0[8] = {}, acc1[8] = {};
    float4 wa[4], wb[4], na[4], nb[4];
#pragma unroll
    for (int k = 0; k < 4; ++k) {
        wa[k] = *(const float4*)(w0p + k * 4);
        wb[k] = *(const float4*)(w1p + k * 4);
    }
    for (int s = 0; s < DSZ / 16; ++s) {
        if (s < DSZ / 16 - 1) {
            int cn = (s + 1) * 16;
#pragma unroll
            for (int k = 0; k < 4; ++k) {
                na[k] = *(const float4*)(w0p + cn + k * 4);
                nb[k] = *(const float4*)(w1p + cn + k * 4);
            }
        }
        int c = s * 16;
#pragma unroll
        for (int j = 0; j < 8; ++j) {
            const float* xp = &xL[b0 + j][c];
#pragma unroll
            for (int k = 0; k < 4; ++k) {
                float4 xv = *(const float4*)(xp + k * 4);
                acc0[j] += wa[k].x * xv.x + wa[k].y * xv.y + wa[k].z * xv.z + wa[k].w * xv.w;
                acc1[j] += wb[k].x * xv.x + wb[k].y * xv.y + wb[k].z * xv.z + wb[k].w * xv.w;
            }
        }
#pragma unroll
        for (int k = 0; k < 4; ++k) { wa[k] = na[k]; wb[k] = nb[k]; }
    }
#pragma unroll
    for (int j = 0; j < 8; ++j) {
        gih[(size_t)r0 * BSZ + b0 + j] = acc0[j];
        gih[(size_t)(r0 + 64) * BSZ + b0 + j] = acc1[j];
    }
}

// GRU finalize: gates + output. 32 blocks x 256 thr; idx = d*32 + b (coalesced gih reads).
__global__ void k_grufin(const float* __restrict__ gih,
                         const float* __restrict__ b_ih, const float* __restrict__ b_hh,
                         const float* __restrict__ lasth,
                         float* __restrict__ u, float* __restrict__ u0,
                         float* __restrict__ hid) {
    int idx = blockIdx.x * 256 + threadIdx.x;    // 8192
    int b = idx & 31, d = idx >> 5;
    float gi0 = gih[(size_t)(0 * DSZ + d) * BSZ + b] + b_ih[0 * DSZ + d];
    float gi1 = gih[(size_t)(1 * DSZ + d) * BSZ + b] + b_ih[1 * DSZ + d];
    float gi2 = gih[(size_t)(2 * DSZ + d) * BSZ + b] + b_ih[2 * DSZ + d];
    float gh0 = gih[(size_t)(3 * DSZ + d) * BSZ + b] + b_hh[0 * DSZ + d];
    float gh1 = gih[(size_t)(4 * DSZ + d) * BSZ + b] + b_hh[1 * DSZ + d];
    float gh2 = gih[(size_t)(5 * DSZ + d) * BSZ + b] + b_hh[2 * DSZ + d];
    float r = 1.f / (1.f + expf(-(gi0 + gh0)));
    float z = 1.f / (1.f + expf(-(gi1 + gh1)));
    float n = tanhf(gi2 + r * gh2);
    float h = lasth[b * DSZ + d];
    float hn = (1.f - z) * n + z * h;
    int o = b * DSZ + d;
    u[o] = hn;
    u0[o] = hn;
    hid[o] = hn;
}

// ---------------------------------------------------------------------------
// pp[p][b] = dot(pos_table[p], u[b])
__global__ void k_posproj(const float* __restrict__ pos_table,
                          const float* __restrict__ u, float* __restrict__ pp) {
    int idx = blockIdx.x * 256 + threadIdx.x;
    if (idx >= PSZ * BSZ) return;
    int p = idx >> 5;
    int b = idx & 31;
    const float* row = pos_table + (size_t)p * DSZ;
    const float* ub = u + b * DSZ;
    float acc = 0.f;
    for (int j = 0; j < DSZ; j += 4) {
        float4 rv = *(const float4*)(row + j);
        float4 uv = *(const float4*)(ub + j);
        acc += rv.x * uv.x + rv.y * uv.y + rv.z * uv.z + rv.w * uv.w;
    }
    pp[idx] = acc;
}

// ---------------------------------------------------------------------------
// proj[v][b] = dot(C[h][v], u[b]).  Row-per-lane streamer, 250 blocks.
__global__ __launch_bounds__(256) void k_proj3(const float* __restrict__ Ct,
                                               const float* __restrict__ u,
                                               float* __restrict__ proj) {
    __shared__ float xL[BSZ][DSZ];
    int t = threadIdx.x;
    const float4* u4 = (const float4*)u;
    for (int i = t; i < BSZ * 64; i += 256) {
        int b = i >> 6, c4 = i & 63;
        *(float4*)&xL[b][c4 * 4] = u4[b * 64 + c4];
    }
    __syncthreads();
    int lane = t & 63, bg = t >> 6, b0 = bg * 8;
    int v0 = blockIdx.x * 128 + lane;
    const float* w0p = Ct + (size_t)v0 * DSZ;
    const float* w1p = w0p + (size_t)64 * DSZ;
    float acc0[8] = {}, acc1[8] = {};
    float4 wa[4], wb[4], na[4], nb[4];
#pragma unroll
    for (int k = 0; k < 4; ++k) {
        wa[k] = *(const float4*)(w0p + k * 4);
        wb[k] = *(const float4*)(w1p + k * 4);
    }
    for (int s = 0; s < DSZ / 16; ++s) {
        if (s < DSZ / 16 - 1) {
            int cn = (s + 1) * 16;
#pragma unroll
            for (int k = 0; k < 4; ++k) {
                na[k] = *(const float4*)(w0p + cn + k * 4);
                nb[k] = *(const float4*)(w1p + cn + k * 4);
            }
        }
        int c = s * 16;
#pragma unroll
        for (int j = 0; j < 8; ++j) {
            const float* xp = &xL[b0 + j][c];
#pragma unroll
            for (int k = 0; k < 4; ++k) {
                float4 xv = *(const float4*)(xp + k * 4);
                acc0[j] += wa[k].x * xv.x + wa[k].y * xv.y + wa[k].z * xv.z + wa[k].w * xv.w;
                acc1[j] += wb[k].x * xv.x + wb[k].y * xv.y + wb[k].z * xv.z + wb[k].w * xv.w;
            }
        }
#pragma unroll
        for (int k = 0; k < 4; ++k) { wa[k] = na[k]; wb[k] = nb[k]; }
    }
#pragma unroll
    for (int j = 0; j < 8; ++j) {
        proj[(size_t)v0 * BSZ + b0 + j] = acc0[j];
        proj[(size_t)(v0 + 64) * BSZ + b0 + j] = acc1[j];
    }
}

// ---------------------------------------------------------------------------
// scores: 128 blocks x 256 thr, idx = m*32+b (coalesced story/sc).
// Also zeroes w (hop<2). hop2 writes logits to out (layout [b][m]).
__global__ void k_scores(const int* __restrict__ story, const int* __restrict__ pos,
                         const float* __restrict__ proj, const float* __restrict__ pp,
                         float* __restrict__ sc, float* __restrict__ w,
                         float* __restrict__ outlg, int hop) {
    int idx = blockIdx.x * 256 + threadIdx.x;    // 32768
    if (hop < 2) {
        float4 z4 = make_float4(0.f, 0.f, 0.f, 0.f);
        float4* wz = (float4*)w + (size_t)idx * 8;
#pragma unroll
        for (int k = 0; k < 8; ++k) wz[k] = z4;
    }
    int b = idx & 31, m = idx >> 5;
    int4 st = *(const int4*)&story[(size_t)idx * TSZ];
    float s = proj[(size_t)st.x * BSZ + b] + proj[(size_t)st.y * BSZ + b] +
              proj[(size_t)st.z * BSZ + b] + proj[(size_t)st.w * BSZ + b];
    if (hop == 0) s += pp[pos[idx] * BSZ + b];
    if (hop == 2) outlg[b * MSZ + m] = s;
    else sc[idx] = s;
}

// ---------------------------------------------------------------------------
// softmax (per b, all M in block) + scatter prob into w[v][b] via atomics.
__global__ void k_softscat(const int* __restrict__ story, const float* __restrict__ sc,
                           float* __restrict__ w) {
    int b = blockIdx.x;
    int m = threadIdx.x;
    __shared__ float red[16];
    float s = sc[m * BSZ + b];
    float mx = s;
#pragma unroll
    for (int o = 32; o > 0; o >>= 1) mx = fmaxf(mx, __shfl_xor(mx, o, 64));
    int wid = m >> 6, lane = m & 63;
    if (lane == 0) red[wid] = mx;
    __syncthreads();
    if (m == 0) {
        float a = red[0];
        for (int i = 1; i < 16; ++i) a = fmaxf(a, red[i]);
        red[0] = a;
    }
    __syncthreads();
    float bm = red[0];
    __syncthreads();
    float e = expf(s - bm);
    float sm = e;
#pragma unroll
    for (int o = 32; o > 0; o >>= 1) sm += __shfl_xor(sm, o, 64);
    if (lane == 0) red[wid] = sm;
    __syncthreads();
    if (m == 0) {
        float a = 0.f;
        for (int i = 0; i < 16; ++i) a += red[i];
        red[0] = a;
    }
    __syncthreads();
    float p = e / red[0];
    int4 st = *(const int4*)&story[(size_t)(m * BSZ + b) * TSZ];
    atomicAdd(&w[(size_t)st.x * BSZ + b], p);
    atomicAdd(&w[(size_t)st.y * BSZ + b], p);
    atomicAdd(&w[(size_t)st.z * BSZ + b], p);
    atomicAdd(&w[(size_t)st.w * BSZ + b], p);
}

// ---------------------------------------------------------------------------
// ok rank-update GEMM: part[blk][b][d] = sum_{v in blk's 128 rows} w[v][b] * C[v][d].
// 250 blocks x 256 thr (64 d-quads x 4 b-groups). Streams C once, coalesced.
__global__ __launch_bounds__(256) void k_okgemm(const float* __restrict__ Ct,
                                                const float* __restrict__ w,
                                                float* __restrict__ part) {
    int t = threadIdx.x, lane = t & 63, bg = t >> 6, b0 = bg * 8;
    int v0 = blockIdx.x * 128;
    float4 acc[8] = {};
    float4 cv = ((const float4*)(Ct + (size_t)v0 * DSZ))[lane];
    float4 wv0 = *(const float4*)&w[(size_t)v0 * BSZ + b0];
    float4 wv1 = *(const float4*)&w[(size_t)v0 * BSZ + b0 + 4];
    for (int r = 0; r < 128; ++r) {
        float4 c = cv;
        float w0x = wv0.x, w0y = wv0.y, w0z = wv0.z, w0w = wv0.w;
        float w1x = wv1.x, w1y = wv1.y, w1z = wv1.z, w1w = wv1.w;
        if (r < 127) {
            int v = v0 + r + 1;
            cv = ((const float4*)(Ct + (size_t)v * DSZ))[lane];
            wv0 = *(const float4*)&w[(size_t)v * BSZ + b0];
            wv1 = *(const float4*)&w[(size_t)v * BSZ + b0 + 4];
        }
        acc[0].x += w0x * c.x; acc[0].y += w0x * c.y; acc[0].z += w0x * c.z; acc[0].w += w0x * c.w;
        acc[1].x += w0y * c.x; acc[1].y += w0y * c.y; acc[1].z += w0y * c.z; acc[1].w += w0y * c.w;
        acc[2].x += w0z * c.x; acc[2].y += w0z * c.y; acc[2].z += w0z * c.z; acc[2].w += w0z * c.w;
        acc[3].x += w0w * c.x; acc[3].y += w0w * c.y; acc[3].z += w0w * c.z; acc[3].w += w0w * c.w;
        acc[4].x += w1x * c.x; acc[4].y += w1x * c.y; acc[4].z += w1x * c.z; acc[4].w += w1x * c.w;
        acc[5].x += w1y * c.x; acc[5].y += w1y * c.y; acc[5].z += w1y * c.z; acc[5].w += w1y * c.w;
        acc[6].x += w1z * c.x; acc[6].y += w1z * c.y; acc[6].z += w1z * c.z; acc[6].w += w1z * c.w;
        acc[7].x += w1w * c.x; acc[7].y += w1w * c.y; acc[7].z += w1w * c.z; acc[7].w += w1w * c.w;
    }
#pragma unroll
    for (int j = 0; j < 8; ++j)
        *(float4*)&part[((size_t)blockIdx.x * BSZ + b0 + j) * DSZ + lane * 4] = acc[j];
}

// reduce 250 partials -> o_k; u += o_k; save ok0 at hop 0.
__global__ void k_okred(const float* __restrict__ part, float* __restrict__ u,
                        float* __restrict__ ok0, int save0) {
    int idx = blockIdx.x * 256 + threadIdx.x;    // B*D = 8192
    float s = 0.f;
    for (int c = 0; c < 250; ++c) s += part[(size_t)c * (BSZ * DSZ) + idx];
    if (save0) ok0[idx] = s;
    u[idx] += s;
}

// ---------------------------------------------------------------------------
// p_vocab row-per-lane streamer: 250 blocks x 256 thr.
__global__ __launch_bounds__(256) void k_pvocab3(const float* __restrict__ u0,
                                                 const float* __restrict__ ok0,
                                                 const float* __restrict__ W1w,
                                                 const float* __restrict__ W1b,
                                                 float* __restrict__ out_pv) {
    __shared__ float xL[BSZ][2 * DSZ];
    int t = threadIdx.x;
    const float4* u04 = (const float4*)u0;
    const float4* ok4 = (const float4*)ok0;
    for (int i = t; i < BSZ * 128; i += 256) {
        int b = i >> 7, c4 = i & 127;
        float4 v = (c4 < 64) ? u04[b * 64 + c4] : ok4[b * 64 + (c4 - 64)];
        *(float4*)&xL[b][c4 * 4] = v;
    }
    __syncthreads();
    int lane = t & 63, bg = t >> 6, b0 = bg * 8;
    int v0 = blockIdx.x * 128 + lane;
    const float* w0p = W1w + (size_t)v0 * 512;
    const float* w1p = w0p + (size_t)64 * 512;
    float acc0[8] = {}, acc1[8] = {};
    float4 wa[4], wb[4], na[4], nb[4];
#pragma unroll
    for (int k = 0; k < 4; ++k) {
        wa[k] = *(const float4*)(w0p + k * 4);
        wb[k] = *(const float4*)(w1p + k * 4);
    }
    for (int s = 0; s < 32; ++s) {
        if (s < 31) {
            int cn = (s + 1) * 16;
#pragma unroll
            for (int k = 0; k < 4; ++k) {
                na[k] = *(const float4*)(w0p + cn + k * 4);
                nb[k] = *(const float4*)(w1p + cn + k * 4);
            }
        }
        int c = s * 16;
#pragma unroll
        for (int j = 0; j < 8; ++j) {
            const float* xp = &xL[b0 + j][c];
#pragma unroll
            for (int k = 0; k < 4; ++k) {
                float4 xv = *(const float4*)(xp + k * 4);
                acc0[j] += wa[k].x * xv.x + wa[k].y * xv.y + wa[k].z * xv.z + wa[k].w * xv.w;
                acc1[j] += wb[k].x * xv.x + wb[k].y * xv.y + wb[k].z * xv.z + wb[k].w * xv.w;
            }
        }
#pragma unroll
        for (int k = 0; k < 4; ++k) { wa[k] = na[k]; wb[k] = nb[k]; }
    }
    float bias0 = W1b[v0], bias1 = W1b[v0 + 64];
#pragma unroll
    for (int j = 0; j < 8; ++j) {
        out_pv[(size_t)(b0 + j) * VSZ + v0] = acc0[j] + bias0;
        out_pv[(size_t)(b0 + j) * VSZ + v0 + 64] = acc1[j] + bias1;
    }
}

// ---------------------------------------------------------------------------
extern "C" void kernel_launch(void* const* d_in, const int* in_sizes, int n_in,
                              void* d_out, int out_size, void* d_ws, size_t ws_size,
                              hipStream_t stream) {
    const int*   story  = (const int*)d_in[0];
    const int*   encq   = (const int*)d_in[1];
    const float* lasth  = (const float*)d_in[2];
    const float* C      = (const float*)d_in[3];
    const float* postab = (const float*)d_in[4];
    const float* W1w    = (const float*)d_in[5];
    const float* W1b    = (const float*)d_in[6];
    const float* gwih   = (const float*)d_in[7];
    const float* gwhh   = (const float*)d_in[8];
    const float* gbih   = (const float*)d_in[9];
    const float* gbhh   = (const float*)d_in[10];

    float* out = (float*)d_out;
    float* wsf = (float*)d_ws;
    int*   pos  = (int*)d_ws;
    float* u    = wsf + OFF_U;
    float* u0   = wsf + OFF_U0;
    float* ok0  = wsf + OFF_OK0;
    float* pp   = wsf + OFF_PP;
    float* gih  = wsf + OFF_GIH;
    float* sc   = wsf + OFF_SC;
    float* w    = wsf + OFF_W;
    float* part = wsf + OFF_PART;
    float* proj = wsf + OFF_PROJ;

    k_positions<<<BSZ, MSZ, 0, stream>>>(story, pos);
    k_gruMV<<<12, 256, 0, stream>>>(encq, lasth, C, gwih, gwhh, gih);
    k_grufin<<<32, 256, 0, stream>>>(gih, gbih, gbhh, lasth, u, u0, out + OUT_HID);
    k_posproj<<<(PSZ * BSZ + 255) / 256, 256, 0, stream>>>(postab, u, pp);

    for (int hop = 0; hop < HOPS; ++hop) {
        k_proj3<<<VSZ / 128, 256, 0, stream>>>(C + (size_t)hop * VD, u, proj);
        k_scores<<<BSZ * MSZ / 256, 256, 0, stream>>>(story, pos, proj, pp, sc, w, out, hop);
        if (hop == 2) break;
        k_softscat<<<BSZ, MSZ, 0, stream>>>(story, sc, w);
        k_okgemm<<<VSZ / 128, 256, 0, stream>>>(C + (size_t)(hop + 1) * VD, w, part);
        k_okred<<<BSZ * DSZ / 256, 256, 0, stream>>>(part, u, ok0, hop == 0 ? 1 : 0);
        if (hop == 0) {
            k_pvocab3<<<VSZ / 128, 256, 0, stream>>>(u0, ok0, W1w, W1b, out + OUT_PV);
        }
    }
}